// Round 8
// baseline (982.247 us; speedup 1.0000x reference)
//
#include <hip/hip_runtime.h>
#include <stdint.h>

#define NN 100000
#define NE 1600000
#define MAXD 64

using short8 = __attribute__((ext_vector_type(8))) short;
using f32x4  = __attribute__((ext_vector_type(4))) float;
using u32x4  = __attribute__((ext_vector_type(4))) unsigned int;
typedef unsigned short ushort_t;

__device__ __forceinline__ ushort_t f2bf(float f){
  union { float f; uint32_t u; } v; v.f = f;
  uint32_t u = v.u;
  uint32_t r = (u + 0x7fffu + ((u >> 16) & 1u)) >> 16;
  return (ushort_t)r;
}
__device__ __forceinline__ float bf2f(ushort_t h){
  union { uint32_t u; float f; } v; v.u = ((uint32_t)h) << 16;
  return v.f;
}

// ---------------- dtype detect: int64 edge_index has all-zero odd words ----
__global__ void k_detect(const unsigned* ei, int* flag){
  __shared__ int any;
  if(threadIdx.x == 0) any = 0;
  __syncthreads();
  unsigned w = ei[2*threadIdx.x + 1];
  if(w) atomicOr(&any, 1);
  __syncthreads();
  if(threadIdx.x == 0) *flag = (any == 0) ? 1 : 0;   // 1 => int64
}

// ---------------- per-node edge list (append) ------------------------------
__global__ void k_build(const int* ei, const int* flag, int* cursor, int* list){
  int e = blockIdx.x * blockDim.x + threadIdx.x;
  if(e >= NE) return;
  bool i64 = (*flag != 0);
  int src, dst;
  if(i64){
    const long long* p = (const long long*)ei;
    src = (int)p[e]; dst = (int)p[NE + e];
  } else {
    src = ei[e]; dst = ei[NE + e];
  }
  if((unsigned)src >= NN || (unsigned)dst >= NN) return;
  int pos = atomicAdd(&cursor[dst], 1);
  if(pos < MAXD) list[dst*MAXD + pos] = src;
}

// ---------------- weight fragment prep -------------------------------------
__global__ void k_wcatfrag(const float* wa, ushort_t* dst, int C, int KT){
  int idx = blockIdx.x*blockDim.x + threadIdx.x;
  int total = 16*KT*64*8;
  if(idx >= total) return;
  int j = idx & 7, lane = (idx>>3)&63;
  int rest = idx >> 9;
  int kt = rest % KT, nt = rest / KT;
  int k = kt*32 + ((lane>>4)<<3) + j;
  int n = nt*16 + (lane & 15);
  float v = 0.f;
  if(k < C) v = (n < 128) ? (wa[k*128+n] - wa[(C+k)*128+n]) : wa[(C+k)*128 + (n-128)];
  dst[idx] = f2bf(v);
}

__global__ void k_wbfrag(const float* wb, ushort_t* dst){
  int idx = blockIdx.x*blockDim.x + threadIdx.x;     // 8*4*64*8 = 16384
  if(idx >= 8*4*64*8) return;
  int j = idx & 7, lane = (idx>>3)&63;
  int kt = (idx>>9)&3, nt = idx>>11;
  int k = kt*32 + ((lane>>4)<<3) + j;
  int n = nt*16 + (lane & 15);
  dst[idx] = f2bf(wb[k*128 + n]);
}

// ---------------- table GEMM: [A | B] = x @ Wcat (+bias on A half) ---------
template<int KT, int ROWLEN, bool SPLIT>
__global__ __launch_bounds__(256)
void k_gemm(const void* xin_, const ushort_t* __restrict__ wfrag,
            const float* __restrict__ bias, float* __restrict__ Atab,
            ushort_t* __restrict__ Btab)
{
  constexpr int K  = KT*32;
  constexpr int RB = K*2 + 16;              // padded LDS row stride, bytes
  __shared__ ushort_t shHi[64*RB/2];
  __shared__ ushort_t shLo[SPLIT ? 64*RB/2 : 2];

  const int t = threadIdx.x;
  const int wave = t >> 6, lane = t & 63;
  const int l15 = lane & 15, lg = lane >> 4;

  short8 bf[4][KT];
  #pragma unroll
  for(int ntl=0; ntl<4; ntl++)
    #pragma unroll
    for(int kt=0; kt<KT; kt++){
      int nt = wave*4 + ntl;
      bf[ntl][kt] = *(const short8*)&wfrag[((nt*KT + kt)*64 + lane)*8];
    }
  float bv[4] = {0.f,0.f,0.f,0.f};
  if(wave < 2){
    #pragma unroll
    for(int ntl=0; ntl<4; ntl++) bv[ntl] = bias[wave*64 + ntl*16 + l15];
  }

  const int row0 = blockIdx.x * 64;

  constexpr int GROUPS = 64*(K/8);
  #pragma unroll
  for(int it=0; it<GROUPS/256; it++){
    int gi  = t + it*256;
    int row = gi / (K/8), kg = gi % (K/8);
    int gr  = row0 + row;
    int off = (row*RB + kg*16) >> 1;
    if constexpr (SPLIT){
      const float* xin = (const float*)xin_;
      short8 hi8, lo8;
      #pragma unroll
      for(int j=0;j<8;j++){
        int k = kg*8 + j;
        float v = (gr < NN && k < ROWLEN) ? xin[(size_t)gr*ROWLEN + k] : 0.f;
        ushort_t h = f2bf(v);
        hi8[j] = (short)h;
        lo8[j] = (short)f2bf(v - bf2f(h));
      }
      *(short8*)&shHi[off] = hi8;
      *(short8*)&shLo[off] = lo8;
    } else {
      const ushort_t* xb = (const ushort_t*)xin_;
      short8 h8 = {0,0,0,0,0,0,0,0};
      if(gr < NN) h8 = *(const short8*)&xb[(size_t)gr*ROWLEN + kg*8];
      *(short8*)&shHi[off] = h8;
    }
  }
  __syncthreads();

  #pragma unroll
  for(int mc=0; mc<4; mc++){
    f32x4 acc[4];
    #pragma unroll
    for(int ntl=0; ntl<4; ntl++) acc[ntl] = (f32x4){0.f,0.f,0.f,0.f};
    #pragma unroll
    for(int kt=0; kt<KT; kt++){
      int off = ((mc*16 + l15)*RB + kt*64 + lg*16) >> 1;
      short8 ah = *(const short8*)&shHi[off];
      #pragma unroll
      for(int ntl=0; ntl<4; ntl++)
        acc[ntl] = __builtin_amdgcn_mfma_f32_16x16x32_bf16(ah, bf[ntl][kt], acc[ntl], 0,0,0);
      if constexpr (SPLIT){
        short8 al = *(const short8*)&shLo[off];
        #pragma unroll
        for(int ntl=0; ntl<4; ntl++)
          acc[ntl] = __builtin_amdgcn_mfma_f32_16x16x32_bf16(al, bf[ntl][kt], acc[ntl], 0,0,0);
      }
    }
    #pragma unroll
    for(int ntl=0; ntl<4; ntl++){
      #pragma unroll
      for(int q=0; q<4; q++){
        int gr = row0 + mc*16 + lg*4 + q;
        if(gr < NN){
          if(wave < 2){
            int ch = wave*64 + ntl*16 + l15;
            Atab[(size_t)gr*128 + ch] = acc[ntl][q] + bv[ntl];
          } else {
            int ch = (wave-2)*64 + ntl*16 + l15;
            Btab[(size_t)gr*128 + ch] = f2bf(acc[ntl][q]);
          }
        }
      }
    }
  }
}

// ---------------- edge kernel: 2-wave team per node, NO LDS, NO barriers ---
// out[n] = relu(max_e relu(A[n]+B[src]) @ wb + bb)
// R4-verified insight: with lane=(r=lane&15, qq=lane>>4), the h values a
// lane computes ARE the MFMA A-fragment (af[i] covers k=i*32+qq*8+j) — no
// LDS round-trip, no barrier. Each of the block's 2 waves owns 4 of the 8
// output tiles (wf = 64 VGPR, loaded ONCE per block lifetime) and
// redundantly computes the full h fragment (h VALU is cheap). Grid-stride
// keeps wf persistent across nodes; B prefetched across chunks.
template<bool F32OUT>
__global__ __launch_bounds__(128, 3)
void k_edge(const float* __restrict__ Atab, const ushort_t* __restrict__ Btab,
            const ushort_t* __restrict__ wbfrag, const float* __restrict__ bias2,
            const int* __restrict__ deg, const int* __restrict__ list,
            float* __restrict__ outF, ushort_t* __restrict__ outB)
{
  const int wv   = threadIdx.x >> 6;      // 0/1 -> output tiles wv*4 .. wv*4+3
  const int lane = threadIdx.x & 63;
  const int r  = lane & 15;               // edge row within chunk
  const int qq = lane >> 4;               // k-subgroup

  // W fragments for this wave's 4 nt tiles: loaded once, live across nodes
  short8 wf[16];
  #pragma unroll
  for(int j=0; j<4; ++j)
    #pragma unroll
    for(int kt=0; kt<4; ++kt)
      wf[j*4+kt] = *(const short8*)&wbfrag[(((wv*4+j)*4 + kt)*64 + lane)*8];

  float bb[4];
  #pragma unroll
  for(int j=0; j<4; ++j) bb[j] = bias2[(wv*4+j)*16 + r];

  for(int n = blockIdx.x; n < NN; n += gridDim.x){
    int d = deg[n]; if(d > MAXD) d = MAXD;
    if(d == 0){
      if(lane < 16){
        #pragma unroll
        for(int j=0; j<4; ++j){
          if(F32OUT) outF[(size_t)n*128 + (wv*4+j)*16 + lane] = 0.f;
          else       outB[(size_t)n*128 + (wv*4+j)*16 + lane] = 0;
        }
      }
      continue;
    }
    const int* lst = &list[(size_t)n*MAXD];

    // this lane's 32 A channels: k = i*32 + qq*8 + (0..7), bias pre-folded
    float ax[4][8];
    #pragma unroll
    for(int i=0;i<4;i++){
      f32x4 lo = *(const f32x4*)&Atab[(size_t)n*128 + i*32 + qq*8];
      f32x4 hi = *(const f32x4*)&Atab[(size_t)n*128 + i*32 + qq*8 + 4];
      #pragma unroll
      for(int j=0;j<4;j++){ ax[i][j] = lo[j]; ax[i][4+j] = hi[j]; }
    }

    f32x4 mac[4];
    #pragma unroll
    for(int j=0;j<4;j++)
      mac[j] = (f32x4){-3.0e38f,-3.0e38f,-3.0e38f,-3.0e38f};

    int nch = (d + 15) >> 4;
    int e0 = (r < d) ? r : d - 1;         // pad by replication
    int s = lst[e0];
    short8 bw[4];
    #pragma unroll
    for(int i=0;i<4;i++)
      bw[i] = *(const short8*)&Btab[(size_t)s*128 + i*32 + qq*8];

    for(int c = 0; c < nch; ++c){
      // ---- h fragments: af[i] = relu(A + B) packed bf16, MFMA A layout ----
      short8 af[4];
      #pragma unroll
      for(int i=0; i<4; ++i){
        union { short8 s8; uint32_t u[4]; } ub; ub.s8 = bw[i];
        union { u32x4 u4; short8 s8; } pk;
        #pragma unroll
        for(int w2=0; w2<4; ++w2){
          uint32_t u = ub.u[w2];
          float flo = __uint_as_float(u << 16);
          float fhi = __uint_as_float(u & 0xffff0000u);
          float hlo = fmaxf(ax[i][2*w2]   + flo, 0.f);
          float hhi = fmaxf(ax[i][2*w2+1] + fhi, 0.f);
          uint32_t pw;
          asm("v_cvt_pk_bf16_f32 %0, %1, %2" : "=v"(pw) : "v"(hlo), "v"(hhi));
          pk.u4[w2] = pw;
        }
        af[i] = pk.s8;
      }

      // ---- prefetch next chunk's B rows (flies under MFMA + next h) ----
      if(c + 1 < nch){
        int e2 = (c+1)*16 + r; if(e2 >= d) e2 = d - 1;
        s = lst[e2];
        #pragma unroll
        for(int i=0;i<4;i++)
          bw[i] = *(const short8*)&Btab[(size_t)s*128 + i*32 + qq*8];
      }

      // ---- MFMA: this wave's 4 nt tiles x K=128, W from registers ----
      f32x4 acc[4];
      #pragma unroll
      for(int j=0;j<4;j++) acc[j] = (f32x4){0.f,0.f,0.f,0.f};
      #pragma unroll
      for(int kt=0; kt<4; ++kt){
        #pragma unroll
        for(int j=0;j<4;++j)
          acc[j] = __builtin_amdgcn_mfma_f32_16x16x32_bf16(af[kt], wf[j*4+kt], acc[j], 0,0,0);
      }
      #pragma unroll
      for(int j=0;j<4;++j){
        #pragma unroll
        for(int q=0;q<4;q++)
          mac[j][q] = fmaxf(mac[j][q], acc[j][q]);
      }
    }

    // ---- epilogue: reduce 16 edge rows (4 in-lane + qq groups), store ----
    #pragma unroll
    for(int j=0; j<4; ++j){
      float m = fmaxf(fmaxf(mac[j][0],mac[j][1]), fmaxf(mac[j][2],mac[j][3]));
      m = fmaxf(m, __shfl_xor(m, 16, 64));
      m = fmaxf(m, __shfl_xor(m, 32, 64));
      float v = fmaxf(m + bb[j], 0.f);
      if(lane < 16){
        if(F32OUT) outF[(size_t)n*128 + (wv*4+j)*16 + lane] = v;
        else       outB[(size_t)n*128 + (wv*4+j)*16 + lane] = f2bf(v);
      }
    }
  }
}

// ---------------- final: concat -> maxpool(24) -> dot(fw)+fb ---------------
template<bool F32IN>
__global__ __launch_bounds__(256)
void k_final(const void* x2_, const void* x4_, const void* x6_,
             const float* __restrict__ fw, const float* __restrict__ fb,
             float* __restrict__ out)
{
  __shared__ float arr[4][384];
  int wave = threadIdx.x >> 6, lane = threadIdx.x & 63;
  int n = blockIdx.x*4 + wave;
  if(n < NN){
    const void* xs[3] = {x2_, x4_, x6_};
    #pragma unroll
    for(int tt=0; tt<3; tt++){
      float a, b;
      if(F32IN){
        const float* p = (const float*)xs[tt] + (size_t)n*128 + lane*2;
        a = p[0]; b = p[1];
      } else {
        const ushort_t* p = (const ushort_t*)xs[tt] + (size_t)n*128 + lane*2;
        a = bf2f(p[0]); b = bf2f(p[1]);
      }
      arr[wave][tt*128 + lane*2]     = a;
      arr[wave][tt*128 + lane*2 + 1] = b;
    }
  }
  __syncthreads();
  if(n < NN && lane < 16){
    float m = -3.0e38f;
    #pragma unroll
    for(int j=0;j<24;j++) m = fmaxf(m, arr[wave][lane*24 + j]);
    float p = m * fw[lane];
    #pragma unroll
    for(int off=1; off<16; off<<=1) p += __shfl_xor(p, off, 64);
    if(lane == 0) out[n] = p + fb[0];
  }
}

// ---------------- host ------------------------------------------------------
extern "C" void kernel_launch(void* const* d_in, const int* in_sizes, int n_in,
                              void* d_out, int out_size, void* d_ws, size_t ws_size,
                              hipStream_t stream)
{
  const float* x   = (const float*)d_in[0];
  const void*  ei  = d_in[1];
  const float* w1a = (const float*)d_in[2];
  const float* b1a = (const float*)d_in[3];
  const float* w1b = (const float*)d_in[4];
  const float* b1b = (const float*)d_in[5];
  const float* w2a = (const float*)d_in[6];
  const float* b2a = (const float*)d_in[7];
  const float* w2b = (const float*)d_in[8];
  const float* b2b = (const float*)d_in[9];
  const float* w3a = (const float*)d_in[10];
  const float* b3a = (const float*)d_in[11];
  const float* w3b = (const float*)d_in[12];
  const float* b3b = (const float*)d_in[13];
  const float* fw  = (const float*)d_in[14];
  const float* fb  = (const float*)d_in[15];

  char* ws = (char*)d_ws;
  size_t off = 0;
  auto alloc = [&](size_t bytes) -> void* {
    void* p = ws + off;
    off = (off + bytes + 255) & ~(size_t)255;
    return p;
  };
  int*      flag   = (int*)alloc(4);
  int*      cursor = (int*)alloc((size_t)NN*4);
  int*      list   = (int*)alloc((size_t)NN*MAXD*4);
  float*    Atab   = (float*)alloc((size_t)NN*128*4);
  ushort_t* Btab   = (ushort_t*)alloc((size_t)NN*128*2);
  ushort_t* wf1    = (ushort_t*)alloc(16*1*64*8*2);
  ushort_t* wf2    = (ushort_t*)alloc(16*4*64*8*2);
  ushort_t* wf3    = (ushort_t*)alloc(16*4*64*8*2);
  ushort_t* wbf1   = (ushort_t*)alloc(8*4*64*8*2);
  ushort_t* wbf2   = (ushort_t*)alloc(8*4*64*8*2);
  ushort_t* wbf3   = (ushort_t*)alloc(8*4*64*8*2);

  size_t fixed = off;
  bool planA = (ws_size >= fixed + 3*(size_t)NN*128*4 + 1024);
  void *x2, *x4, *x6;
  size_t xbytes = planA ? (size_t)NN*128*4 : (size_t)NN*128*2;
  x2 = alloc(xbytes); x4 = alloc(xbytes); x6 = alloc(xbytes);

  hipMemsetAsync(cursor, 0, (size_t)NN*4, stream);
  k_detect<<<1, 128, 0, stream>>>((const unsigned*)ei, flag);
  k_build<<<(NE + 255)/256, 256, 0, stream>>>((const int*)ei, flag, cursor, list);

  k_wcatfrag<<<(16*1*64*8 + 255)/256, 256, 0, stream>>>(w1a, wf1, 24, 1);
  k_wcatfrag<<<(16*4*64*8 + 255)/256, 256, 0, stream>>>(w2a, wf2, 128, 4);
  k_wcatfrag<<<(16*4*64*8 + 255)/256, 256, 0, stream>>>(w3a, wf3, 128, 4);
  k_wbfrag<<<64, 256, 0, stream>>>(w1b, wbf1);
  k_wbfrag<<<64, 256, 0, stream>>>(w2b, wbf2);
  k_wbfrag<<<64, 256, 0, stream>>>(w3b, wbf3);

  const int GT = (NN + 63)/64;
  const int EG = 4096;

  k_gemm<1,24,true><<<GT, 256, 0, stream>>>(x, wf1, b1a, Atab, Btab);
  if(planA){
    k_edge<true><<<EG, 128, 0, stream>>>(Atab, Btab, wbf1, b1b, cursor, list, (float*)x2, nullptr);
    k_gemm<4,128,true><<<GT, 256, 0, stream>>>(x2, wf2, b2a, Atab, Btab);
    k_edge<true><<<EG, 128, 0, stream>>>(Atab, Btab, wbf2, b2b, cursor, list, (float*)x4, nullptr);
    k_gemm<4,128,true><<<GT, 256, 0, stream>>>(x4, wf3, b3a, Atab, Btab);
    k_edge<true><<<EG, 128, 0, stream>>>(Atab, Btab, wbf3, b3b, cursor, list, (float*)x6, nullptr);
    k_final<true><<<(NN + 3)/4, 256, 0, stream>>>(x2, x4, x6, fw, fb, (float*)d_out);
  } else {
    k_edge<false><<<EG, 128, 0, stream>>>(Atab, Btab, wbf1, b1b, cursor, list, nullptr, (ushort_t*)x2);
    k_gemm<4,128,false><<<GT, 256, 0, stream>>>(x2, wf2, b2a, Atab, Btab);
    k_edge<false><<<EG, 128, 0, stream>>>(Atab, Btab, wbf2, b2b, cursor, list, nullptr, (ushort_t*)x4);
    k_gemm<4,128,false><<<GT, 256, 0, stream>>>(x4, wf3, b3a, Atab, Btab);
    k_edge<false><<<EG, 128, 0, stream>>>(Atab, Btab, wbf3, b3b, cursor, list, nullptr, (ushort_t*)x6);
    k_final<false><<<(NN + 3)/4, 256, 0, stream>>>(x2, x4, x6, fw, fb, (float*)d_out);
  }
}